// Round 10
// baseline (269.076 us; speedup 1.0000x reference)
//
#include <hip/hip_runtime.h>
#include <hip/hip_bf16.h>

// Problem: B=16, S=4096, H=1024
//   energy = tanh(x @ W^T + b); scores = softmax(energy, axis=S); out = sum_S scores*x
// GEMM view: M = B*S = 65536, N = H = 1024, K = H = 1024.
#define Bsz  16
#define Sdim 4096
#define Hdim 1024
#define Mtot (Bsz * Sdim)   // 65536
#define Kdim Hdim
#define Ndim Hdim

// ---- tile geometry (256^2, BK=32, 8 waves 2Mx4N, 2-slot ring, R5 schedule) ----
#define BM2 256
#define BN2 256
#define MT2 (Mtot / BM2)    // 256
#define NT2 (Ndim / BN2)    // 4
#define NKT32 (Kdim / 32)   // 32 K-tiles

typedef short s16x8 __attribute__((ext_vector_type(8)));
typedef float f32x4 __attribute__((ext_vector_type(4)));

__device__ __forceinline__ unsigned short f2bf(float f) {
  __hip_bfloat16 h = __float2bfloat16(f);
  unsigned short u;
  __builtin_memcpy(&u, &h, 2);
  return u;
}
__device__ __forceinline__ s16x8 cvt8(float4 u, float4 v) {
  s16x8 r;
  r[0] = (short)f2bf(u.x); r[1] = (short)f2bf(u.y);
  r[2] = (short)f2bf(u.z); r[3] = (short)f2bf(u.w);
  r[4] = (short)f2bf(v.x); r[5] = (short)f2bf(v.y);
  r[6] = (short)f2bf(v.z); r[7] = (short)f2bf(v.w);
  return r;
}

// async global->LDS, 16B per lane; LDS dest is wave-uniform base + lane*16
__device__ __forceinline__ void gload_lds16(const unsigned short* g, unsigned short* l) {
  __builtin_amdgcn_global_load_lds(
      (const __attribute__((address_space(1))) unsigned int*)g,
      (__attribute__((address_space(3))) unsigned int*)l,
      16, 0, 0);
}

// ---- kernel 1: W fp32 [N][K] -> row-major bf16 Wb (2 MB) ----
__global__ __launch_bounds__(256) void wconv_kernel(const float* __restrict__ W,
                                                    unsigned short* __restrict__ Wb) {
  int i = blockIdx.x * 256 + threadIdx.x;
  float4 v = reinterpret_cast<const float4*>(W)[i];
  ushort4 o;
  o.x = f2bf(v.x); o.y = f2bf(v.y); o.z = f2bf(v.z); o.w = f2bf(v.w);
  reinterpret_cast<ushort4*>(Wb)[i] = o;
}

// =====================================================================
// kernel 2: 256^2, BK=32, R5's best-measured schedule, with the X
// fp32->bf16 conversion FUSED into A-staging (no xconv pre-pass, no Xb).
//
// 512 thr = 8 waves (2 wm x 4 wn); per-wave output 128x64; 16x16x32 MFMA.
// A-staging (replaces gload_lds): per tile, each thread loads 4x float4
// of X fp32 (rows tid>>1, 16-elem half (tid&1)), cvt8 -> 2x s16x8,
// ds_write_b128 into the swizzled [256][32] layout. The cvt+write work
// sits in idle issue slots of a latency-bound kernel (both pipes <36%).
// B-staging: gload_lds from Wb (R5-proven, inverse-swizzled source).
//
// Barriers/waits = R5's proven best (4 barriers/tile, MID = bar +
// lgkmcnt(0) + sched_barrier; the lgkmcnt(0) now also covers the A
// ds_writes, which precede it and are consumed only after END).
// vmcnt(0) at tile end drains the 2 B-gloads issued ~1000cy earlier
// (L2-hot W panel => near-free).
//
// L2 locality: the 4 same-mt blocks (sharing the X A-panel, 1 MB fp32)
// land on ONE XCD under this swizzle (their bids differ by 8), so X is
// HBM-read once; epilogue re-reads the same rows L2-warm.
// =====================================================================
__global__ __launch_bounds__(512, 2) void attn_main(
    const float* __restrict__ X,            // [Mtot][Kdim] fp32
    const unsigned short* __restrict__ Wb,  // [Ndim][Kdim] bf16
    const float* __restrict__ bias,         // [Ndim]
    float* __restrict__ lpart,              // [MT2][Ndim]
    float* __restrict__ cpart) {            // [MT2][Ndim]
  __shared__ unsigned short Abf[2][BM2 * 32];  // 32 KB
  __shared__ unsigned short Bbf[2][BN2 * 32];  // 32 KB
  __shared__ float red[2][2][BN2];             // 4 KB -> 68 KB total

  // XCD-chunked bijective swizzle (nwg=1024, 1024%8==0)
  int bid = blockIdx.x;
  int swz = (bid & 7) * (MT2 * NT2 / 8) + (bid >> 3);
  const int mt = swz >> 2;
  const int nt = swz & 3;
  const int m0 = mt * BM2;
  const int n0 = nt * BN2;

  const int tid = threadIdx.x;
  const int l   = tid & 63;
  const int w   = tid >> 6;
  const int wm  = w >> 2;         // 0..1 (M half)
  const int wn  = w & 3;          // 0..3 (N quarter)
  const int lr  = l & 15;
  const int lk  = l >> 4;

  f32x4 acc[8][4];
#pragma unroll
  for (int i = 0; i < 8; i++)
#pragma unroll
    for (int j = 0; j < 4; j++) acc[i][j] = (f32x4){0.f, 0.f, 0.f, 0.f};

  // ---- A staging: fp32 source + swizzled LDS write addresses ----
  const int ra = tid >> 1;              // row 0..255
  const int ch = tid & 1;               // 16-elem half
  const float* gaP = X + (size_t)(m0 + ra) * Kdim + ch * 16;
  const int xa = (ra >> 1) & 3;         // swizzle key
  const int swA0 = ra * 32 + (((ch * 2 + 0) ^ xa) << 3);
  const int swA1 = ra * 32 + (((ch * 2 + 1) ^ xa) << 3);

  // ---- B staging source (inverse-swizzled, R5-proven) ----
  const int srow = w * 16 + (l >> 2);
  const int scol = (((l & 3) ^ ((l >> 3) & 3)) << 3);
  const unsigned short* srcB0 = Wb + (size_t)(n0 + srow) * Kdim + scol;

  // ---- fragment read offsets (R5-proven zero-conflict pattern) ----
  int offA[2][4], offB[4];
#pragma unroll
  for (int mh = 0; mh < 2; mh++)
#pragma unroll
    for (int j = 0; j < 4; j++) {
      const int r = wm * 128 + mh * 64 + j * 16 + lr;
      offA[mh][j] = r * 32 + ((lk ^ ((r >> 1) & 3)) << 3);
    }
#pragma unroll
  for (int n = 0; n < 4; n++) {
    const int rn = wn * 64 + n * 16 + lr;
    offB[n] = rn * 32 + ((lk ^ ((rn >> 1) & 3)) << 3);
  }

#define STAGE_B(slot, tp) do {                                          \
    unsigned short* d = &Bbf[slot][w * 512];                            \
    const unsigned short* g = srcB0 + (size_t)(tp) * 32;                \
    gload_lds16(g, d);                                                  \
    gload_lds16(g + (size_t)128 * Kdim, d + 4096);                      \
  } while (0)

#define MID_BARRIER() do {                                   \
    asm volatile("" ::: "memory");                           \
    __builtin_amdgcn_s_barrier();                            \
    asm volatile("s_waitcnt lgkmcnt(0)" ::: "memory");       \
    __builtin_amdgcn_sched_barrier(0);                       \
  } while (0)
#define END_BARRIER() do {                                   \
    asm volatile("" ::: "memory");                           \
    __builtin_amdgcn_s_barrier();                            \
  } while (0)

  // ---- prologue: stage tile 0 (A fp32->cvt->LDS, B gload); full drain once ----
  {
    float4 g0 = *(const float4*)(gaP + 0);
    float4 g1 = *(const float4*)(gaP + 4);
    float4 g2 = *(const float4*)(gaP + 8);
    float4 g3 = *(const float4*)(gaP + 12);
    STAGE_B(0, 0);
    *(s16x8*)&Abf[0][swA0] = cvt8(g0, g1);
    *(s16x8*)&Abf[0][swA1] = cvt8(g2, g3);
  }
  __syncthreads();

  s16x8 bf[4];

  // ---- main loop: 32 K-tiles x 2 phases (R5 schedule) ----
  for (int t = 0; t < NKT32; ++t) {
    const int cur = t & 1, nxt = cur ^ 1;
    const unsigned short* As = Abf[cur];
    const unsigned short* Bs = Bbf[cur];
    const bool more = (t + 1 < NKT32);
    s16x8 af[4];
    float4 g0, g1, g2, g3;

    // ===== phase 0: mh0 + B read; issue A(t+1) fp32 loads + B(t+1) gload =====
#pragma unroll
    for (int j = 0; j < 4; ++j) af[j] = *(const s16x8*)&As[offA[0][j]];
#pragma unroll
    for (int n = 0; n < 4; ++n) bf[n] = *(const s16x8*)&Bs[offB[n]];
    if (more) {
      const float* ap = gaP + (t + 1) * 32;
      g0 = *(const float4*)(ap + 0);
      g1 = *(const float4*)(ap + 4);
      g2 = *(const float4*)(ap + 8);
      g3 = *(const float4*)(ap + 12);
      STAGE_B(nxt, t + 1);
    }
    MID_BARRIER();
    __builtin_amdgcn_s_setprio(1);
#pragma unroll
    for (int j = 0; j < 4; ++j)
#pragma unroll
      for (int n = 0; n < 4; ++n)
        acc[j][n] = __builtin_amdgcn_mfma_f32_16x16x32_bf16(af[j], bf[n], acc[j][n], 0, 0, 0);
    __builtin_amdgcn_s_setprio(0);
    END_BARRIER();

    // ===== phase 1: mh1; cvt + ds_write A(t+1) into the other slot =====
#pragma unroll
    for (int j = 0; j < 4; ++j) af[j] = *(const s16x8*)&As[offA[1][j]];
    if (more) {
      *(s16x8*)&Abf[nxt][swA0] = cvt8(g0, g1);   // waits ga loads (auto vmcnt)
      *(s16x8*)&Abf[nxt][swA1] = cvt8(g2, g3);
    }
    MID_BARRIER();   // lgkmcnt(0) also covers the A ds_writes above
    __builtin_amdgcn_s_setprio(1);
#pragma unroll
    for (int j = 0; j < 4; ++j)
#pragma unroll
      for (int n = 0; n < 4; ++n)
        acc[4 + j][n] = __builtin_amdgcn_mfma_f32_16x16x32_bf16(af[j], bf[n], acc[4 + j][n], 0, 0, 0);
    __builtin_amdgcn_s_setprio(0);
    if (more) asm volatile("s_waitcnt vmcnt(0)" ::: "memory");  // B(t+1) resident (L2-hot)
    END_BARRIER();
  }

  // ---- epilogue: e = tanh(acc+bias); l = sum exp(e), c = sum exp(e)*x ----
  // C/D layout: col = lane&15, row = (lane>>4)*4 + reg.
  // acc[m8] rows: wm*128 + (m8>>2)*64 + (m8&3)*16. tanh bounded -> no max sub.
  float lsum[4], csum[4];
#pragma unroll
  for (int nr = 0; nr < 4; nr++) {
    const int o = n0 + wn * 64 + nr * 16 + lr;
    const float bv = bias[o];
    float lacc = 0.f, cacc = 0.f;
#pragma unroll
    for (int m8 = 0; m8 < 8; m8++) {
      const int sr = m0 + wm * 128 + (m8 >> 2) * 64 + (m8 & 3) * 16 + lk * 4;
#pragma unroll
      for (int r = 0; r < 4; r++) {
        float e  = acc[m8][nr][r] + bv;
        float t  = __expf(2.f * e);
        float th = 1.f - __fdividef(2.f, t + 1.f);  // tanh(e); e bounded ~[-7,7]
        float sc = __expf(th);                      // in [0.37, 2.72]
        float xv = X[(size_t)(sr + r) * Kdim + o];  // fp32, L2-warm
        lacc += sc;
        cacc += sc * xv;
      }
    }
    lacc += __shfl_xor(lacc, 16); lacc += __shfl_xor(lacc, 32);
    cacc += __shfl_xor(cacc, 16); cacc += __shfl_xor(cacc, 32);
    lsum[nr] = lacc; csum[nr] = cacc;
  }

  if (lk == 0) {
#pragma unroll
    for (int nr = 0; nr < 4; nr++) {
      red[wm][0][wn * 64 + nr * 16 + lr] = lsum[nr];
      red[wm][1][wn * 64 + nr * 16 + lr] = csum[nr];
    }
  }
  __syncthreads();
  if (tid < BN2) {
    float L = red[0][0][tid] + red[1][0][tid];
    float C = red[0][1][tid] + red[1][1][tid];
    lpart[(size_t)mt * Ndim + n0 + tid] = L;
    cpart[(size_t)mt * Ndim + n0 + tid] = C;
  }
}

// ---- kernel 3: combine s-chunks -> out[b][o] ----
__global__ __launch_bounds__(256) void finalize_kernel(const float* __restrict__ lpart,
                                                       const float* __restrict__ cpart,
                                                       float* __restrict__ out, int chunks) {
  int i = blockIdx.x * 256 + threadIdx.x;
  int b = i >> 10, o = i & 1023;
  float L = 0.f, C = 0.f;
  for (int sc = 0; sc < chunks; ++sc) {
    size_t idx = (size_t)(b * chunks + sc) * Ndim + o;
    L += lpart[idx];
    C += cpart[idx];
  }
  out[i] = C / L;
}

extern "C" void kernel_launch(void* const* d_in, const int* in_sizes, int n_in,
                              void* d_out, int out_size, void* d_ws, size_t ws_size,
                              hipStream_t stream) {
  const float* X    = (const float*)d_in[0];
  const float* W    = (const float*)d_in[1];
  const float* bias = (const float*)d_in[2];
  float* out = (float*)d_out;

  // ws: Wb bf16 (2 MB) | lpart f32 [256*1024] (1 MB) | cpart (1 MB)
  unsigned short* Wb = (unsigned short*)d_ws;
  float* lpart = (float*)((char*)d_ws + (size_t)Ndim * Kdim * 2);
  float* cpart = lpart + (size_t)MT2 * Ndim;

  wconv_kernel<<<dim3(Ndim * Kdim / 1024), dim3(256), 0, stream>>>(W, Wb);
  attn_main<<<dim3(MT2 * NT2), dim3(512), 0, stream>>>(X, Wb, bias, lpart, cpart);
  finalize_kernel<<<dim3(Bsz * Hdim / 256), dim3(256), 0, stream>>>(lpart, cpart, out,
                                                                    Sdim / BM2);
}